// Round 1
// baseline (172.836 us; speedup 1.0000x reference)
//
#include <hip/hip_runtime.h>
#include <cstdint>

typedef short s16x8 __attribute__((ext_vector_type(8)));
typedef float f32x4 __attribute__((ext_vector_type(4)));
using u16 = unsigned short;

// ---- problem constants ----
// B=8, N=512, D=512, H=8, dh=64, HID=2048
// outputs: x_hat [8,512,512], P [8,8,512,512], S [8,8,512,512]  (f32)

__device__ __forceinline__ u16 f2bf(float f) {
    union { float f; uint32_t u; } v; v.f = f;
    uint32_t u = v.u;
    return (u16)((u + 0x7FFFu + ((u >> 16) & 1u)) >> 16);
}

// ---------------------------------------------------------------------------
// f32 -> bf16 conversion of x, Wq, Wk, Wv, W1, W2 (one fused kernel)
// vec4 segment boundaries: x 524288 | Wq 65536 | Wk 65536 | Wv 65536 | W1 262144 | W2 262144
// ---------------------------------------------------------------------------
__global__ __launch_bounds__(256) void k_convert(
    const float* __restrict__ x, const float* __restrict__ wq,
    const float* __restrict__ wk, const float* __restrict__ wv,
    const float* __restrict__ w1, const float* __restrict__ w2,
    u16* __restrict__ xb, u16* __restrict__ wqb, u16* __restrict__ wkb,
    u16* __restrict__ wvb, u16* __restrict__ w1b, u16* __restrict__ w2b)
{
    long g = (long)blockIdx.x * 256 + threadIdx.x;  // float4 index
    const float* src; u16* dst; long off;
    if      (g <  524288) { src = x;  dst = xb;  off = g; }
    else if (g <  589824) { src = wq; dst = wqb; off = g -  524288; }
    else if (g <  655360) { src = wk; dst = wkb; off = g -  589824; }
    else if (g <  720896) { src = wv; dst = wvb; off = g -  655360; }
    else if (g <  983040) { src = w1; dst = w1b; off = g -  720896; }
    else                  { src = w2; dst = w2b; off = g -  983040; }
    float4 v = ((const float4*)src)[off];
    ushort4 o;
    o.x = f2bf(v.x); o.y = f2bf(v.y); o.z = f2bf(v.z); o.w = f2bf(v.w);
    ((ushort4*)dst)[off] = o;
}

// ---------------------------------------------------------------------------
// sigma: sigT[b][h][n] = softplus(x[b,n,:]·Wsig[h,:] + bsig[h]) + 1e-5
// one wave per (b,n) row
// ---------------------------------------------------------------------------
__global__ __launch_bounds__(256) void k_sigma(
    const float* __restrict__ x, const float* __restrict__ Wsig,
    const float* __restrict__ bsig, float* __restrict__ sigT)
{
    int row  = (int)((blockIdx.x * 256 + threadIdx.x) >> 6);  // 0..4095 = b*512+n
    int lane = threadIdx.x & 63;
    const float4* xr = (const float4*)(x + (long)row * 512);
    float4 xa = xr[lane * 2], xc = xr[lane * 2 + 1];
    float xs[8] = {xa.x, xa.y, xa.z, xa.w, xc.x, xc.y, xc.z, xc.w};
    float ph[8];
#pragma unroll
    for (int h = 0; h < 8; ++h) {
        const float4* wr = (const float4*)(Wsig + h * 512);
        float4 wa = wr[lane * 2], wc = wr[lane * 2 + 1];
        ph[h] = xs[0]*wa.x + xs[1]*wa.y + xs[2]*wa.z + xs[3]*wa.w
              + xs[4]*wc.x + xs[5]*wc.y + xs[6]*wc.z + xs[7]*wc.w;
    }
#pragma unroll
    for (int h = 0; h < 8; ++h)
#pragma unroll
        for (int m = 1; m < 64; m <<= 1)
            ph[h] += __shfl_xor(ph[h], m, 64);
    if (lane < 8) {
        float z  = ph[lane] + bsig[lane];
        float sp = fmaxf(z, 0.f) + log1pf(__expf(-fabsf(z)));
        int b = row >> 9, n = row & 511;
        sigT[(((long)b * 8 + lane) << 9) + n] = sp + 1e-5f;
    }
}

// ---------------------------------------------------------------------------
// Gaussian prior P: P[row][m] = exp(-(n-m)^2/(2 s^2)) / rowsum   (prefactor cancels)
// one wave per (b,h,n) row
// ---------------------------------------------------------------------------
__global__ __launch_bounds__(256) void k_prior(
    const float* __restrict__ sigT, float* __restrict__ P)
{
    int row  = (int)((blockIdx.x * 256 + threadIdx.x) >> 6);  // 0..32767
    int lane = threadIdx.x & 63;
    int n = row & 511;
    float s = sigT[row];
    float a = -1.0f / (2.0f * s * s);
    float e[8]; float sum = 0.f;
#pragma unroll
    for (int j = 0; j < 8; ++j) {
        int m = lane + (j << 6);
        float d = (float)(n - m);
        e[j] = __expf(a * d * d);
        sum += e[j];
    }
#pragma unroll
    for (int m = 1; m < 64; m <<= 1) sum += __shfl_xor(sum, m, 64);
    float r = 1.0f / sum;
    long base = (long)row * 512;
#pragma unroll
    for (int j = 0; j < 8; ++j)
        P[base + lane + (j << 6)] = e[j] * r;
}

// ---------------------------------------------------------------------------
// generic NT MFMA GEMM: C[i][j] = epi( sum_k A[i][k]*B[j][k] )
// A: bf16(u16) or f32 (converted during staging); B: bf16(u16)
// 256 threads = 4 waves (WM x WN), 16x16x32 bf16 MFMA fragments
// EPI: 0 = +bias, bf16 -> Q/K head layout [(b*8+h)*512+n]*64+d
//      1 = +bias, bf16 -> V transposed   [(b*8+h)*64+d]*512+n
//      2 = f32 -> Zh[b][n][h*64+d]   (batch z = b*8+h)
//      3 = +bias, relu, bf16 row-major ld=2048
//      4 = +bias, f32 row-major ld=512
// ---------------------------------------------------------------------------
template<int BM, int BN, int BK, int WM, int WN, int EPI, typename TA>
__global__ __launch_bounds__(256) void k_gemm_nt(
    const TA* __restrict__ A, const u16* __restrict__ B,
    const float* __restrict__ bias, void* __restrict__ C,
    int lda, int ldb, int K, long sA, long sB)
{
    constexpr int LDP = BK + 8;
    __shared__ u16 As[BM][LDP];
    __shared__ u16 Bs[BN][LDP];

    const TA*  Ag = A + (long)blockIdx.z * sA + (long)blockIdx.x * BM * lda;
    const u16* Bg = B + (long)blockIdx.z * sB + (long)blockIdx.y * BN * ldb;

    int tid  = threadIdx.x;
    int wave = tid >> 6, lane = tid & 63;
    int wm = wave / WN, wn = wave % WN;
    constexpr int WTM = BM / WM, WTN = BN / WN;
    constexpr int FM = WTM / 16, FN = WTN / 16;

    f32x4 acc[FM][FN];
#pragma unroll
    for (int i = 0; i < FM; ++i)
#pragma unroll
        for (int j = 0; j < FN; ++j) acc[i][j] = (f32x4){0.f, 0.f, 0.f, 0.f};

    for (int k0 = 0; k0 < K; k0 += BK) {
        __syncthreads();
        constexpr int ACH = BM * BK / 8 / 256;
#pragma unroll
        for (int c = 0; c < ACH; ++c) {
            int id = c * 256 + tid;
            int r = id / (BK / 8), c8 = id % (BK / 8);
            if constexpr (sizeof(TA) == 4) {
                const float* p = (const float*)(Ag + (long)r * lda + k0 + c8 * 8);
                float4 v0 = *(const float4*)p;
                float4 v1 = *(const float4*)(p + 4);
                s16x8 o;
                o[0] = (short)f2bf(v0.x); o[1] = (short)f2bf(v0.y);
                o[2] = (short)f2bf(v0.z); o[3] = (short)f2bf(v0.w);
                o[4] = (short)f2bf(v1.x); o[5] = (short)f2bf(v1.y);
                o[6] = (short)f2bf(v1.z); o[7] = (short)f2bf(v1.w);
                *(s16x8*)&As[r][c8 * 8] = o;
            } else {
                *(s16x8*)&As[r][c8 * 8] = *(const s16x8*)(Ag + (long)r * lda + k0 + c8 * 8);
            }
        }
        constexpr int BCH = BN * BK / 8 / 256;
#pragma unroll
        for (int c = 0; c < BCH; ++c) {
            int id = c * 256 + tid;
            int r = id / (BK / 8), c8 = id % (BK / 8);
            *(s16x8*)&Bs[r][c8 * 8] = *(const s16x8*)(Bg + (long)r * ldb + k0 + c8 * 8);
        }
        __syncthreads();
#pragma unroll
        for (int kk = 0; kk < BK / 32; ++kk) {
            s16x8 af[FM], bfr[FN];
#pragma unroll
            for (int fm = 0; fm < FM; ++fm)
                af[fm] = *(const s16x8*)&As[wm * WTM + fm * 16 + (lane & 15)][kk * 32 + (lane >> 4) * 8];
#pragma unroll
            for (int fn = 0; fn < FN; ++fn)
                bfr[fn] = *(const s16x8*)&Bs[wn * WTN + fn * 16 + (lane & 15)][kk * 32 + (lane >> 4) * 8];
#pragma unroll
            for (int fm = 0; fm < FM; ++fm)
#pragma unroll
                for (int fn = 0; fn < FN; ++fn)
                    acc[fm][fn] = __builtin_amdgcn_mfma_f32_16x16x32_bf16(af[fm], bfr[fn], acc[fm][fn], 0, 0, 0);
        }
    }

    int i0 = blockIdx.x * BM + wm * WTM;
    int j0 = blockIdx.y * BN + wn * WTN;
#pragma unroll
    for (int fm = 0; fm < FM; ++fm)
#pragma unroll
        for (int fn = 0; fn < FN; ++fn)
#pragma unroll
            for (int j = 0; j < 4; ++j) {
                int gi = i0 + fm * 16 + ((lane >> 4) << 2) + j;
                int gj = j0 + fn * 16 + (lane & 15);
                float v = acc[fm][fn][j];
                if constexpr (EPI == 0) {
                    v += bias[gj];
                    int h = gj >> 6, d = gj & 63, b = gi >> 9, n = gi & 511;
                    ((u16*)C)[(((long)(b * 8 + h) * 512 + n) << 6) + d] = f2bf(v);
                } else if constexpr (EPI == 1) {
                    v += bias[gj];
                    int h = gj >> 6, d = gj & 63, b = gi >> 9, n = gi & 511;
                    ((u16*)C)[(((long)(b * 8 + h) * 64 + d) << 9) + n] = f2bf(v);
                } else if constexpr (EPI == 2) {
                    int z = blockIdx.z, b = z >> 3, h = z & 7;
                    ((float*)C)[(((long)b * 512 + gi) << 9) + h * 64 + gj] = v;
                } else if constexpr (EPI == 3) {
                    v = fmaxf(v + bias[gj], 0.f);
                    ((u16*)C)[(long)gi * 2048 + gj] = f2bf(v);
                } else {  // EPI == 4
                    ((float*)C)[(long)gi * 512 + gj] = v + bias[gj];
                }
            }
}

// ---------------------------------------------------------------------------
// attention scores + softmax -> S (f32, written to d_out)
// block = 4 waves, one (b,h), 64 rows (16 per wave); full 512-col strip in regs
// ---------------------------------------------------------------------------
__global__ __launch_bounds__(256) void k_attn(
    const u16* __restrict__ Qb, const u16* __restrict__ Kb, float* __restrict__ S)
{
    int bh = blockIdx.y;   // 0..63
    int rb = blockIdx.x;   // 0..7
    int tid = threadIdx.x;
    int wave = tid >> 6, lane = tid & 63;

    __shared__ u16 Qs[64][72];
    __shared__ u16 Ks[128][72];

    const u16* Qg = Qb + ((long)bh * 512 + rb * 64) * 64;
    const u16* Kg = Kb + (long)bh * 512 * 64;

#pragma unroll
    for (int c = 0; c < 2; ++c) {
        int id = c * 256 + tid;
        int r = id >> 3, c8 = id & 7;
        *(s16x8*)&Qs[r][c8 * 8] = *(const s16x8*)(Qg + r * 64 + c8 * 8);
    }

    f32x4 acc[32];
#pragma unroll
    for (int t = 0; t < 32; ++t) acc[t] = (f32x4){0.f, 0.f, 0.f, 0.f};

    int arow = wave * 16 + (lane & 15);
    int k8 = (lane >> 4) * 8;

#pragma unroll
    for (int ch = 0; ch < 4; ++ch) {
        __syncthreads();
#pragma unroll
        for (int c = 0; c < 4; ++c) {
            int id = c * 256 + tid;
            int r = id >> 3, c8 = id & 7;
            *(s16x8*)&Ks[r][c8 * 8] = *(const s16x8*)(Kg + (long)(ch * 128 + r) * 64 + c8 * 8);
        }
        __syncthreads();
#pragma unroll
        for (int kk = 0; kk < 2; ++kk) {
            s16x8 a = *(const s16x8*)&Qs[arow][kk * 32 + k8];
#pragma unroll
            for (int fn = 0; fn < 8; ++fn) {
                s16x8 b = *(const s16x8*)&Ks[fn * 16 + (lane & 15)][kk * 32 + k8];
                acc[ch * 8 + fn] = __builtin_amdgcn_mfma_f32_16x16x32_bf16(a, b, acc[ch * 8 + fn], 0, 0, 0);
            }
        }
    }

    float mx[4] = {-1e30f, -1e30f, -1e30f, -1e30f};
#pragma unroll
    for (int t = 0; t < 32; ++t)
#pragma unroll
        for (int j = 0; j < 4; ++j) mx[j] = fmaxf(mx[j], acc[t][j]);
#pragma unroll
    for (int j = 0; j < 4; ++j)
#pragma unroll
        for (int m = 1; m < 16; m <<= 1) mx[j] = fmaxf(mx[j], __shfl_xor(mx[j], m, 64));

    float sum[4] = {0.f, 0.f, 0.f, 0.f};
#pragma unroll
    for (int t = 0; t < 32; ++t)
#pragma unroll
        for (int j = 0; j < 4; ++j) {
            float p = __expf(0.125f * (acc[t][j] - mx[j]));
            acc[t][j] = p;
            sum[j] += p;
        }
#pragma unroll
    for (int j = 0; j < 4; ++j) {
#pragma unroll
        for (int m = 1; m < 16; m <<= 1) sum[j] += __shfl_xor(sum[j], m, 64);
        sum[j] = 1.0f / sum[j];
    }

    long base = ((long)bh * 512 + rb * 64 + wave * 16) * 512;
    int rloc = (lane >> 4) * 4;
#pragma unroll
    for (int t = 0; t < 32; ++t) {
        int col = t * 16 + (lane & 15);
#pragma unroll
        for (int j = 0; j < 4; ++j)
            S[base + (long)(rloc + j) * 512 + col] = acc[t][j] * sum[j];
    }
}

// ---------------------------------------------------------------------------
// LayerNorm(a + b) * g + beta ; optional bf16 twin output. one wave per row.
// ---------------------------------------------------------------------------
template<bool WBF>
__global__ __launch_bounds__(256) void k_ln(
    const float* __restrict__ a, const float* __restrict__ b,
    const float* __restrict__ g, const float* __restrict__ bt,
    float* __restrict__ y, u16* __restrict__ yb)
{
    int row  = (int)((blockIdx.x * 256 + threadIdx.x) >> 6);
    int lane = threadIdx.x & 63;
    const float4* ar = (const float4*)(a + (long)row * 512);
    const float4* br = (const float4*)(b + (long)row * 512);
    float4 a0 = ar[lane * 2], a1 = ar[lane * 2 + 1];
    float4 b0 = br[lane * 2], b1 = br[lane * 2 + 1];
    float v[8] = {a0.x + b0.x, a0.y + b0.y, a0.z + b0.z, a0.w + b0.w,
                  a1.x + b1.x, a1.y + b1.y, a1.z + b1.z, a1.w + b1.w};
    float s = 0.f, q = 0.f;
#pragma unroll
    for (int j = 0; j < 8; ++j) { s += v[j]; q += v[j] * v[j]; }
#pragma unroll
    for (int m = 1; m < 64; m <<= 1) {
        s += __shfl_xor(s, m, 64);
        q += __shfl_xor(q, m, 64);
    }
    float mean = s * (1.f / 512.f);
    float var  = q * (1.f / 512.f) - mean * mean;
    float rstd = rsqrtf(var + 1e-5f);
    const float4* gr = (const float4*)(g + lane * 8);
    const float4* tr = (const float4*)(bt + lane * 8);
    float4 g0 = gr[0], g1 = gr[1], t0 = tr[0], t1 = tr[1];
    float gg[8] = {g0.x, g0.y, g0.z, g0.w, g1.x, g1.y, g1.z, g1.w};
    float tt[8] = {t0.x, t0.y, t0.z, t0.w, t1.x, t1.y, t1.z, t1.w};
    float o[8];
#pragma unroll
    for (int j = 0; j < 8; ++j) o[j] = (v[j] - mean) * rstd * gg[j] + tt[j];
    float4* yr = (float4*)(y + (long)row * 512 + lane * 8);
    yr[0] = make_float4(o[0], o[1], o[2], o[3]);
    yr[1] = make_float4(o[4], o[5], o[6], o[7]);
    if constexpr (WBF) {
        s16x8 ob;
#pragma unroll
        for (int j = 0; j < 8; ++j) ob[j] = (short)f2bf(o[j]);
        *(s16x8*)(yb + (long)row * 512 + lane * 8) = ob;
    }
}

// ---------------------------------------------------------------------------
extern "C" void kernel_launch(void* const* d_in, const int* in_sizes, int n_in,
                              void* d_out, int out_size, void* d_ws, size_t ws_size,
                              hipStream_t stream)
{
    const float* x    = (const float*)d_in[0];
    const float* Wq   = (const float*)d_in[1];
    const float* bq   = (const float*)d_in[2];
    const float* Wk   = (const float*)d_in[3];
    const float* bk   = (const float*)d_in[4];
    const float* Wv   = (const float*)d_in[5];
    const float* bv   = (const float*)d_in[6];
    const float* Wsig = (const float*)d_in[7];
    const float* bsig = (const float*)d_in[8];
    const float* g1   = (const float*)d_in[9];
    const float* be1  = (const float*)d_in[10];
    const float* W1   = (const float*)d_in[11];
    const float* b1   = (const float*)d_in[12];
    const float* W2   = (const float*)d_in[13];
    const float* b2   = (const float*)d_in[14];
    const float* g2   = (const float*)d_in[15];
    const float* be2  = (const float*)d_in[16];

    float* out_xhat = (float*)d_out;
    float* out_P    = out_xhat + 2097152;
    float* out_S    = out_P + 16777216;

    char* ws = (char*)d_ws;
    // region [0, 16MB) : xb/Qb/Kb/Vt, later reused for `hidden`
    u16*   xb   = (u16*)(ws + 0);
    u16*   Qb   = (u16*)(ws + 4194304);
    u16*   Kb   = (u16*)(ws + 8388608);
    u16*   Vt   = (u16*)(ws + 12582912);
    u16*   hid  = (u16*)(ws + 0);          // aliases xb/Qb/Kb/Vt (dead by then)
    u16*   Wqb  = (u16*)(ws + 16777216);
    u16*   Wkb  = (u16*)(ws + 17301504);
    u16*   Wvb  = (u16*)(ws + 17825792);
    u16*   W1b  = (u16*)(ws + 18350080);
    u16*   W2b  = (u16*)(ws + 20447232);
    float* sigT = (float*)(ws + 22544384);
    float* Zh   = (float*)(ws + 22675456);
    float* x2   = (float*)(ws + 22675456); // aliases Zh (dead after LN1)
    float* Z    = (float*)(ws + 31064064);
    u16*   Zb   = (u16*)(ws + 39452672);
    // total: 43,646,976 bytes

    k_convert<<<4864, 256, 0, stream>>>(x, Wq, Wk, Wv, W1, W2, xb, Wqb, Wkb, Wvb, W1b, W2b);
    k_sigma<<<1024, 256, 0, stream>>>(x, Wsig, bsig, sigT);
    k_prior<<<8192, 256, 0, stream>>>(sigT, out_P);

    // Q,K,V projections (NT, K=512)
    k_gemm_nt<128,128,64,2,2,0,u16><<<dim3(32,4,1),256,0,stream>>>(xb, Wqb, bq, Qb, 512, 512, 512, 0, 0);
    k_gemm_nt<128,128,64,2,2,0,u16><<<dim3(32,4,1),256,0,stream>>>(xb, Wkb, bk, Kb, 512, 512, 512, 0, 0);
    k_gemm_nt<128,128,64,2,2,1,u16><<<dim3(32,4,1),256,0,stream>>>(xb, Wvb, bv, Vt, 512, 512, 512, 0, 0);

    // scores + softmax -> S
    k_attn<<<dim3(8,64),256,0,stream>>>(Qb, Kb, out_S);

    // Zh = S @ V  (batched over b*h, A = f32 S from d_out)
    k_gemm_nt<128,64,64,2,2,2,float><<<dim3(4,1,64),256,0,stream>>>(out_S, Vt, nullptr, Zh, 512, 512, 512, 262144, 32768);

    // Z = LN(Zh + x)  (f32 + bf16 twin)
    k_ln<true><<<1024,256,0,stream>>>(Zh, x, g1, be1, Z, Zb);

    // hidden = relu(Z @ W1^T + b1)  -> bf16
    k_gemm_nt<128,128,64,2,2,3,u16><<<dim3(32,16,1),256,0,stream>>>(Zb, W1b, b1, hid, 512, 512, 512, 0, 0);

    // x2 = hidden @ W2^T + b2  -> f32
    k_gemm_nt<128,128,64,2,2,4,u16><<<dim3(32,4,1),256,0,stream>>>(hid, W2b, b2, x2, 2048, 2048, 2048, 0, 0);

    // x_hat = LN(x2 + Z)
    k_ln<false><<<1024,256,0,stream>>>(x2, Z, g2, be2, out_xhat, nullptr);
}

// Round 3
// 154.417 us; speedup vs baseline: 1.1193x; 1.1193x over previous
//
#include <hip/hip_runtime.h>
#include <cstdint>

typedef short s16x8 __attribute__((ext_vector_type(8)));
typedef float f32x4 __attribute__((ext_vector_type(4)));
using u16 = unsigned short;

// ---- problem constants ----
// B=8, N=512, D=512, H=8, dh=64, HID=2048
// outputs: x_hat [8,512,512], P [8,8,512,512], S [8,8,512,512]  (f32)

__device__ __forceinline__ u16 f2bf(float f) {
    union { float f; uint32_t u; } v; v.f = f;
    uint32_t u = v.u;
    return (u16)((u + 0x7FFFu + ((u >> 16) & 1u)) >> 16);
}

// truncate-pack 8 f32 -> 8 bf16 (2 VALU ops per pair; bias < 2^-8 rel, fine for S in [0,1])
__device__ __forceinline__ s16x8 pack_bf8(f32x4 a, f32x4 b) {
    union { s16x8 s; uint32_t w[4]; } o;
    uint32_t a0 = __float_as_uint(a[0]), a1 = __float_as_uint(a[1]);
    uint32_t a2 = __float_as_uint(a[2]), a3 = __float_as_uint(a[3]);
    uint32_t b0 = __float_as_uint(b[0]), b1 = __float_as_uint(b[1]);
    uint32_t b2 = __float_as_uint(b[2]), b3 = __float_as_uint(b[3]);
    o.w[0] = (a0 >> 16) | (a1 & 0xffff0000u);
    o.w[1] = (a2 >> 16) | (a3 & 0xffff0000u);
    o.w[2] = (b0 >> 16) | (b1 & 0xffff0000u);
    o.w[3] = (b2 >> 16) | (b3 & 0xffff0000u);
    return o.s;
}

// ---------------------------------------------------------------------------
// f32 -> bf16 conversion of x, Wq, Wk, Wv, W1, W2 + bias concat (one kernel)
// vec4 segments: x 524288 | Wq 65536 | Wk 65536 | Wv 65536 | W1 262144 | W2 262144
// tail: 384 vec4 = concat(bq,bk,bv) f32 copy
// ---------------------------------------------------------------------------
__global__ __launch_bounds__(256) void k_convert(
    const float* __restrict__ x, const float* __restrict__ wq,
    const float* __restrict__ wk, const float* __restrict__ wv,
    const float* __restrict__ w1, const float* __restrict__ w2,
    const float* __restrict__ bq, const float* __restrict__ bk,
    const float* __restrict__ bv,
    u16* __restrict__ xb, u16* __restrict__ wqb, u16* __restrict__ wkb,
    u16* __restrict__ wvb, u16* __restrict__ w1b, u16* __restrict__ w2b,
    float* __restrict__ biascat)
{
    long g = (long)blockIdx.x * 256 + threadIdx.x;  // float4 index
    if (g >= 1245184) {
        long id = g - 1245184;
        if (id < 384) {
            const float* src = id < 128 ? bq : id < 256 ? bk : bv;
            ((float4*)biascat)[id] = ((const float4*)src)[id & 127];
        }
        return;
    }
    const float* src; u16* dst; long off;
    if      (g <  524288) { src = x;  dst = xb;  off = g; }
    else if (g <  589824) { src = wq; dst = wqb; off = g -  524288; }
    else if (g <  655360) { src = wk; dst = wkb; off = g -  589824; }
    else if (g <  720896) { src = wv; dst = wvb; off = g -  655360; }
    else if (g <  983040) { src = w1; dst = w1b; off = g -  720896; }
    else                  { src = w2; dst = w2b; off = g -  983040; }
    float4 v = ((const float4*)src)[off];
    ushort4 o;
    o.x = f2bf(v.x); o.y = f2bf(v.y); o.z = f2bf(v.z); o.w = f2bf(v.w);
    ((ushort4*)dst)[off] = o;
}

// ---------------------------------------------------------------------------
// sigma: sigT[b][h][n] = softplus(x[b,n,:]·Wsig[h,:] + bsig[h]) + 1e-5
// one wave per (b,n) row
// ---------------------------------------------------------------------------
__global__ __launch_bounds__(256) void k_sigma(
    const float* __restrict__ x, const float* __restrict__ Wsig,
    const float* __restrict__ bsig, float* __restrict__ sigT)
{
    int row  = (int)((blockIdx.x * 256 + threadIdx.x) >> 6);  // 0..4095 = b*512+n
    int lane = threadIdx.x & 63;
    const float4* xr = (const float4*)(x + (long)row * 512);
    float4 xa = xr[lane * 2], xc = xr[lane * 2 + 1];
    float xs[8] = {xa.x, xa.y, xa.z, xa.w, xc.x, xc.y, xc.z, xc.w};
    float ph[8];
#pragma unroll
    for (int h = 0; h < 8; ++h) {
        const float4* wr = (const float4*)(Wsig + h * 512);
        float4 wa = wr[lane * 2], wc = wr[lane * 2 + 1];
        ph[h] = xs[0]*wa.x + xs[1]*wa.y + xs[2]*wa.z + xs[3]*wa.w
              + xs[4]*wc.x + xs[5]*wc.y + xs[6]*wc.z + xs[7]*wc.w;
    }
#pragma unroll
    for (int h = 0; h < 8; ++h)
#pragma unroll
        for (int m = 1; m < 64; m <<= 1)
            ph[h] += __shfl_xor(ph[h], m, 64);
    if (lane < 8) {
        float z  = ph[lane] + bsig[lane];
        float sp = fmaxf(z, 0.f) + log1pf(__expf(-fabsf(z)));
        int b = row >> 9, n = row & 511;
        sigT[(((long)b * 8 + lane) << 9) + n] = sp + 1e-5f;
    }
}

// ---------------------------------------------------------------------------
// Gaussian prior P: P[row][m] = exp(-(n-m)^2/(2 s^2)) / rowsum (prefactor cancels)
// one wave per (b,h,n) row; each lane owns 8 contiguous cols -> float4 stores
// ---------------------------------------------------------------------------
__global__ __launch_bounds__(256) void k_prior(
    const float* __restrict__ sigT, float* __restrict__ P)
{
    int row  = (int)((blockIdx.x * 256 + threadIdx.x) >> 6);  // 0..32767
    int lane = threadIdx.x & 63;
    int n = row & 511;
    float s = sigT[row];
    float a = -1.0f / (2.0f * s * s);
    float e[8]; float sum = 0.f;
#pragma unroll
    for (int j = 0; j < 8; ++j) {
        float d = (float)(n - (lane * 8 + j));
        e[j] = __expf(a * d * d);
        sum += e[j];
    }
#pragma unroll
    for (int m = 1; m < 64; m <<= 1) sum += __shfl_xor(sum, m, 64);
    float r = 1.0f / sum;
    float4* dst = (float4*)(P + (long)row * 512 + lane * 8);
    dst[0] = make_float4(e[0]*r, e[1]*r, e[2]*r, e[3]*r);
    dst[1] = make_float4(e[4]*r, e[5]*r, e[6]*r, e[7]*r);
}

// ---------------------------------------------------------------------------
// generic NT MFMA GEMM: C[i][j] = epi( sum_k A[i][k]*B[j][k] )
// EPI: 3 = +bias, relu, bf16 row-major ld=2048
//      4 = +bias, f32 row-major ld=512
//      5 = QKV fused: gj 512-band routes to Q-layout / K-layout / V-transposed
// ---------------------------------------------------------------------------
template<int BM, int BN, int BK, int WM, int WN, int EPI, typename TA>
__global__ __launch_bounds__(256) void k_gemm_nt(
    const TA* __restrict__ A, const u16* __restrict__ B,
    const float* __restrict__ bias, void* __restrict__ C,
    int lda, int ldb, int K, long sA, long sB)
{
    constexpr int LDP = BK + 8;
    __shared__ u16 As[BM][LDP];
    __shared__ u16 Bs[BN][LDP];

    const TA*  Ag = A + (long)blockIdx.z * sA + (long)blockIdx.x * BM * lda;
    const u16* Bg = B + (long)blockIdx.z * sB + (long)blockIdx.y * BN * ldb;

    int tid  = threadIdx.x;
    int wave = tid >> 6, lane = tid & 63;
    int wm = wave / WN, wn = wave % WN;
    constexpr int WTM = BM / WM, WTN = BN / WN;
    constexpr int FM = WTM / 16, FN = WTN / 16;

    f32x4 acc[FM][FN];
#pragma unroll
    for (int i = 0; i < FM; ++i)
#pragma unroll
        for (int j = 0; j < FN; ++j) acc[i][j] = (f32x4){0.f, 0.f, 0.f, 0.f};

    for (int k0 = 0; k0 < K; k0 += BK) {
        __syncthreads();
        constexpr int ACH = BM * BK / 8 / 256;
#pragma unroll
        for (int c = 0; c < ACH; ++c) {
            int id = c * 256 + tid;
            int r = id / (BK / 8), c8 = id % (BK / 8);
            *(s16x8*)&As[r][c8 * 8] = *(const s16x8*)(Ag + (long)r * lda + k0 + c8 * 8);
        }
        constexpr int BCH = BN * BK / 8 / 256;
#pragma unroll
        for (int c = 0; c < BCH; ++c) {
            int id = c * 256 + tid;
            int r = id / (BK / 8), c8 = id % (BK / 8);
            *(s16x8*)&Bs[r][c8 * 8] = *(const s16x8*)(Bg + (long)r * ldb + k0 + c8 * 8);
        }
        __syncthreads();
#pragma unroll
        for (int kk = 0; kk < BK / 32; ++kk) {
            s16x8 af[FM], bfr[FN];
#pragma unroll
            for (int fm = 0; fm < FM; ++fm)
                af[fm] = *(const s16x8*)&As[wm * WTM + fm * 16 + (lane & 15)][kk * 32 + (lane >> 4) * 8];
#pragma unroll
            for (int fn = 0; fn < FN; ++fn)
                bfr[fn] = *(const s16x8*)&Bs[wn * WTN + fn * 16 + (lane & 15)][kk * 32 + (lane >> 4) * 8];
#pragma unroll
            for (int fm = 0; fm < FM; ++fm)
#pragma unroll
                for (int fn = 0; fn < FN; ++fn)
                    acc[fm][fn] = __builtin_amdgcn_mfma_f32_16x16x32_bf16(af[fm], bfr[fn], acc[fm][fn], 0, 0, 0);
        }
    }

    int i0 = blockIdx.x * BM + wm * WTM;
    int j0 = blockIdx.y * BN + wn * WTN;
#pragma unroll
    for (int fm = 0; fm < FM; ++fm)
#pragma unroll
        for (int fn = 0; fn < FN; ++fn)
#pragma unroll
            for (int j = 0; j < 4; ++j) {
                int gi = i0 + fm * 16 + ((lane >> 4) << 2) + j;
                int gj = j0 + fn * 16 + (lane & 15);
                float v = acc[fm][fn][j];
                if constexpr (EPI == 3) {
                    v = fmaxf(v + bias[gj], 0.f);
                    ((u16*)C)[(long)gi * 2048 + gj] = f2bf(v);
                } else if constexpr (EPI == 4) {
                    ((float*)C)[(long)gi * 512 + gj] = v + bias[gj];
                } else {  // EPI == 5 : QKV fused epilogue
                    v += bias[gj];
                    int mat = gj >> 9, cj = gj & 511;
                    int h = cj >> 6, d = cj & 63, b = gi >> 9, n = gi & 511;
                    u16* base = (u16*)C;
                    if (mat == 0)
                        base[(((long)(b * 8 + h) * 512 + n) << 6) + d] = f2bf(v);
                    else if (mat == 1)
                        (base + 2097152)[(((long)(b * 8 + h) * 512 + n) << 6) + d] = f2bf(v);
                    else
                        (base + 4194304)[(((long)(b * 8 + h) * 64 + d) << 9) + n] = f2bf(v);
                }
            }
}

// ---------------------------------------------------------------------------
// fused attention: scores -> softmax -> S (global) -> P@V -> Zh
// block = 4 independent waves, one (b,h), 64 rows (16/wave), no __syncthreads.
// Each wave: full 512-col score strip in 128 acc VGPRs; PV via per-wave
// private LDS strip (f32, pad 260 -> 2-way bank aliasing = free), 2 passes.
// ---------------------------------------------------------------------------
__global__ __launch_bounds__(256) void k_attn_pv(
    const u16* __restrict__ Qb, const u16* __restrict__ Kb,
    const u16* __restrict__ Vt, float* __restrict__ S, float* __restrict__ Zh)
{
    __shared__ float Sb[4][16][260];
    int bh = blockIdx.y;   // 0..63
    int rb = blockIdx.x;   // 0..7
    int tid = threadIdx.x;
    int wave = tid >> 6, lane = tid & 63;
    int r16 = lane & 15, g4 = lane >> 4, hi8 = g4 * 8;

    const u16* Qg = Qb + ((long)bh * 512 + rb * 64 + wave * 16) * 64;
    const u16* Kg = Kb + (long)bh * 512 * 64;
    const u16* Vg = Vt + (long)bh * 64 * 512;

    // this wave's two Q fragments (K-dim = 64 = 2x32)
    s16x8 qa[2];
    qa[0] = *(const s16x8*)(Qg + r16 * 64 + hi8);
    qa[1] = *(const s16x8*)(Qg + r16 * 64 + 32 + hi8);

    f32x4 acc[32];
#pragma unroll
    for (int t = 0; t < 32; ++t) acc[t] = (f32x4){0.f, 0.f, 0.f, 0.f};

#pragma unroll
    for (int ch = 0; ch < 4; ++ch)
#pragma unroll
        for (int kk = 0; kk < 2; ++kk)
#pragma unroll
            for (int fn = 0; fn < 8; ++fn) {
                s16x8 b = *(const s16x8*)(Kg + (long)(ch * 128 + fn * 16 + r16) * 64 + kk * 32 + hi8);
                acc[ch * 8 + fn] = __builtin_amdgcn_mfma_f32_16x16x32_bf16(qa[kk], b, acc[ch * 8 + fn], 0, 0, 0);
            }

    // ---- softmax across the 16-lane col groups (row = g4*4+j) ----
    float mx[4] = {-1e30f, -1e30f, -1e30f, -1e30f};
#pragma unroll
    for (int t = 0; t < 32; ++t)
#pragma unroll
        for (int j = 0; j < 4; ++j) mx[j] = fmaxf(mx[j], acc[t][j]);
#pragma unroll
    for (int j = 0; j < 4; ++j)
#pragma unroll
        for (int m = 1; m < 16; m <<= 1) mx[j] = fmaxf(mx[j], __shfl_xor(mx[j], m, 64));

    float sum[4] = {0.f, 0.f, 0.f, 0.f};
#pragma unroll
    for (int t = 0; t < 32; ++t)
#pragma unroll
        for (int j = 0; j < 4; ++j) {
            float p = __expf(0.125f * (acc[t][j] - mx[j]));
            acc[t][j] = p;
            sum[j] += p;
        }
#pragma unroll
    for (int j = 0; j < 4; ++j) {
#pragma unroll
        for (int m = 1; m < 16; m <<= 1) sum[j] += __shfl_xor(sum[j], m, 64);
        sum[j] = 1.0f / sum[j];
    }
#pragma unroll
    for (int t = 0; t < 32; ++t)
#pragma unroll
        for (int j = 0; j < 4; ++j) acc[t][j] *= sum[j];

    // ---- write S (normalized) ----
    long sbase = ((long)bh * 512 + rb * 64 + wave * 16) * 512;
#pragma unroll
    for (int t = 0; t < 32; ++t) {
        int col = t * 16 + r16;
#pragma unroll
        for (int j = 0; j < 4; ++j)
            S[sbase + (long)(g4 * 4 + j) * 512 + col] = acc[t][j];
    }

    // ---- PV: Zh[16 rows][64 d] via LDS round-trip, 2 passes of 256 cols ----
    f32x4 zacc[4];
#pragma unroll
    for (int fn = 0; fn < 4; ++fn) zacc[fn] = (f32x4){0.f, 0.f, 0.f, 0.f};

#pragma unroll
    for (int p = 0; p < 2; ++p) {
#pragma unroll
        for (int t = 0; t < 16; ++t)
#pragma unroll
            for (int j = 0; j < 4; ++j)
                Sb[wave][g4 * 4 + j][t * 16 + r16] = acc[p * 16 + t][j];
        // same-wave RAW on LDS: compiler inserts lgkmcnt wait
#pragma unroll
        for (int kk = 0; kk < 8; ++kk) {
            f32x4 lo = *(const f32x4*)&Sb[wave][r16][kk * 32 + hi8];
            f32x4 hi = *(const f32x4*)&Sb[wave][r16][kk * 32 + hi8 + 4];
            s16x8 pa = pack_bf8(lo, hi);
#pragma unroll
            for (int fn = 0; fn < 4; ++fn) {
                s16x8 vb = *(const s16x8*)(Vg + (long)(fn * 16 + r16) * 512 + p * 256 + kk * 32 + hi8);
                zacc[fn] = __builtin_amdgcn_mfma_f32_16x16x32_bf16(pa, vb, zacc[fn], 0, 0, 0);
            }
        }
    }

    // ---- write Zh[b][n][h*64+d] ----
    long zb = ((long)(bh >> 3) * 512 + rb * 64 + wave * 16) * 512 + (bh & 7) * 64;
#pragma unroll
    for (int fn = 0; fn < 4; ++fn)
#pragma unroll
        for (int j = 0; j < 4; ++j)
            Zh[zb + (long)(g4 * 4 + j) * 512 + fn * 16 + r16] = zacc[fn][j];
}

// ---------------------------------------------------------------------------
// LayerNorm(a + b) * g + beta ; optional bf16 twin output. one wave per row.
// ---------------------------------------------------------------------------
template<bool WBF>
__global__ __launch_bounds__(256) void k_ln(
    const float* __restrict__ a, const float* __restrict__ b,
    const float* __restrict__ g, const float* __restrict__ bt,
    float* __restrict__ y, u16* __restrict__ yb)
{
    int row  = (int)((blockIdx.x * 256 + threadIdx.x) >> 6);
    int lane = threadIdx.x & 63;
    const float4* ar = (const float4*)(a + (long)row * 512);
    const float4* br = (const float4*)(b + (long)row * 512);
    float4 a0 = ar[lane * 2], a1 = ar[lane * 2 + 1];
    float4 b0 = br[lane * 2], b1 = br[lane * 2 + 1];
    float v[8] = {a0.x + b0.x, a0.y + b0.y, a0.z + b0.z, a0.w + b0.w,
                  a1.x + b1.x, a1.y + b1.y, a1.z + b1.z, a1.w + b1.w};
    float s = 0.f, q = 0.f;
#pragma unroll
    for (int j = 0; j < 8; ++j) { s += v[j]; q += v[j] * v[j]; }
#pragma unroll
    for (int m = 1; m < 64; m <<= 1) {
        s += __shfl_xor(s, m, 64);
        q += __shfl_xor(q, m, 64);
    }
    float mean = s * (1.f / 512.f);
    float var  = q * (1.f / 512.f) - mean * mean;
    float rstd = rsqrtf(var + 1e-5f);
    const float4* gr = (const float4*)(g + lane * 8);
    const float4* tr = (const float4*)(bt + lane * 8);
    float4 g0 = gr[0], g1 = gr[1], t0 = tr[0], t1 = tr[1];
    float gg[8] = {g0.x, g0.y, g0.z, g0.w, g1.x, g1.y, g1.z, g1.w};
    float tt[8] = {t0.x, t0.y, t0.z, t0.w, t1.x, t1.y, t1.z, t1.w};
    float o[8];
#pragma unroll
    for (int j = 0; j < 8; ++j) o[j] = (v[j] - mean) * rstd * gg[j] + tt[j];
    float4* yr = (float4*)(y + (long)row * 512 + lane * 8);
    yr[0] = make_float4(o[0], o[1], o[2], o[3]);
    yr[1] = make_float4(o[4], o[5], o[6], o[7]);
    if constexpr (WBF) {
        s16x8 ob;
#pragma unroll
        for (int j = 0; j < 8; ++j) ob[j] = (short)f2bf(o[j]);
        *(s16x8*)(yb + (long)row * 512 + lane * 8) = ob;
    }
}

// ---------------------------------------------------------------------------
extern "C" void kernel_launch(void* const* d_in, const int* in_sizes, int n_in,
                              void* d_out, int out_size, void* d_ws, size_t ws_size,
                              hipStream_t stream)
{
    const float* x    = (const float*)d_in[0];
    const float* Wq   = (const float*)d_in[1];
    const float* bq   = (const float*)d_in[2];
    const float* Wk   = (const float*)d_in[3];
    const float* bk   = (const float*)d_in[4];
    const float* Wv   = (const float*)d_in[5];
    const float* bv   = (const float*)d_in[6];
    const float* Wsig = (const float*)d_in[7];
    const float* bsig = (const float*)d_in[8];
    const float* g1   = (const float*)d_in[9];
    const float* be1  = (const float*)d_in[10];
    const float* W1   = (const float*)d_in[11];
    const float* b1   = (const float*)d_in[12];
    const float* W2   = (const float*)d_in[13];
    const float* b2   = (const float*)d_in[14];
    const float* g2   = (const float*)d_in[15];
    const float* be2  = (const float*)d_in[16];

    float* out_xhat = (float*)d_out;
    float* out_P    = out_xhat + 2097152;
    float* out_S    = out_P + 16777216;

    char* ws = (char*)d_ws;
    u16*   xb   = (u16*)(ws + 0);
    u16*   Qb   = (u16*)(ws + 4194304);   // Qb/Kb/Vt contiguous (EPI5 offsets)
    u16*   hid  = (u16*)(ws + 0);         // aliases xb/Qb/Kb/Vt (dead by then)
    u16*   Wqb  = (u16*)(ws + 16777216);  // Wqb/Wkb/Wvb contiguous = fused B
    u16*   Wkb  = (u16*)(ws + 17301504);
    u16*   Wvb  = (u16*)(ws + 17825792);
    u16*   W1b  = (u16*)(ws + 18350080);
    u16*   W2b  = (u16*)(ws + 20447232);
    float* sigT = (float*)(ws + 22544384); // [22544384, 22675456) — FULLY used
    float* Zh   = (float*)(ws + 22675456);
    float* bcat = (float*)(ws + 22675456); // head of Zh region: written by
                                           // k_convert, read by QKV epilogue,
                                           // only THEN overwritten by Zh.
    float* x2   = (float*)(ws + 22675456); // aliases Zh (dead after LN1)
    float* Z    = (float*)(ws + 31064064);
    u16*   Zb   = (u16*)(ws + 39452672);

    k_convert<<<4866, 256, 0, stream>>>(x, Wq, Wk, Wv, W1, W2, bq, bk, bv,
                                        xb, Wqb, Wkb, Wvb, W1b, W2b, bcat);
    k_sigma<<<1024, 256, 0, stream>>>(x, Wsig, bsig, sigT);
    k_prior<<<8192, 256, 0, stream>>>(sigT, out_P);

    // fused Q|K|V projection: N=1536, B = concat(Wq,Wk,Wv) bf16
    k_gemm_nt<128,128,64,2,2,5,u16><<<dim3(32,12,1),256,0,stream>>>(
        xb, Wqb, bcat, Qb, 512, 512, 512, 0, 0);

    // scores + softmax -> S, then P@V -> Zh (fused)
    k_attn_pv<<<dim3(8,64),256,0,stream>>>(Qb, Qb + 2097152, Qb + 4194304, out_S, Zh);

    // Z = LN(Zh + x)  (f32 + bf16 twin)
    k_ln<true><<<1024,256,0,stream>>>(Zh, x, g1, be1, Z, Zb);

    // hidden = relu(Z @ W1^T + b1)  -> bf16
    k_gemm_nt<128,128,64,2,2,3,u16><<<dim3(32,16,1),256,0,stream>>>(Zb, W1b, b1, hid, 512, 512, 512, 0, 0);

    // x2 = hidden @ W2^T + b2  -> f32  (128x64 tiles -> 256 blocks)
    k_gemm_nt<128,64,64,2,2,4,u16><<<dim3(32,8,1),256,0,stream>>>(hid, W2b, b2, x2, 2048, 2048, 2048, 0, 0);

    // x_hat = LN(x2 + Z)
    k_ln<false><<<1024,256,0,stream>>>(x2, Z, g2, be2, out_xhat, nullptr);
}